// Round 1
// baseline (744.293 us; speedup 1.0000x reference)
//
#include <hip/hip_runtime.h>
#include <stdint.h>

#define D 128
#define K1 384
#define TM 128
#define LDA 136          // padded LDS row stride in bf16 elems (272 B = 17*16B)
#define N_EDGES 800000
#define N_NODES 50000

typedef __attribute__((ext_vector_type(8))) short short8;   // 8 bf16 = 4 VGPRs
typedef __attribute__((ext_vector_type(4))) float f32x4;

__device__ __forceinline__ unsigned int bf16_rne(float f) {
    unsigned int u = __builtin_bit_cast(unsigned int, f);
    return (u + 0x7FFFu + ((u >> 16) & 1u)) >> 16;
}

// ---- prep: cell_attr fp32 -> bf16 (flat, vectorized) ----
__global__ void prep_cell(const float* __restrict__ src, unsigned short* __restrict__ dst, int n4) {
    int i = blockIdx.x * blockDim.x + threadIdx.x;
    if (i >= n4) return;
    float4 v = ((const float4*)src)[i];
    ushort4 o;
    o.x = (unsigned short)bf16_rne(v.x);
    o.y = (unsigned short)bf16_rne(v.y);
    o.z = (unsigned short)bf16_rne(v.z);
    o.w = (unsigned short)bf16_rne(v.w);
    ((ushort4*)dst)[i] = o;
}

// ---- prep: W1 (384x128) -> W1T bf16 (128x384), W2 (128x128) -> W2T bf16 (128x128) ----
__global__ void prep_w(const float* __restrict__ W1, const float* __restrict__ W2,
                       unsigned short* __restrict__ W1T, unsigned short* __restrict__ W2T) {
    int id = blockIdx.x * blockDim.x + threadIdx.x;   // 0 .. 65535
    if (id < K1 * D) {
        int n = id & 127, k = id >> 7;                // id = k*128 + n
        W1T[n * K1 + k] = (unsigned short)bf16_rne(W1[id]);
    } else {
        int id2 = id - K1 * D;
        int n = id2 & 127, k = id2 >> 7;
        W2T[n * D + k] = (unsigned short)bf16_rne(W2[id2]);
    }
}

// ---- fused gather + MLP ----
// out[e][n] = b2[n] + sum_k relu( b1 + [cell[s[e]] | cell[r[e]] | edge[e]] @ W1 )[k] * W2[k][n]
template <bool CELL_BF16>
__global__ __launch_bounds__(256, 2) void edge_mlp(
    const float* __restrict__ cell_f32,
    const unsigned short* __restrict__ cellb,
    const float* __restrict__ edge_attr,
    const unsigned short* __restrict__ W1T,   // [128][384] bf16
    const float* __restrict__ b1,
    const unsigned short* __restrict__ W2T,   // [128][128] bf16
    const float* __restrict__ b2,
    const int* __restrict__ sidx,
    const int* __restrict__ ridx,
    float* __restrict__ out)
{
    __shared__ __align__(16) unsigned short sA[TM * LDA];   // 34816 B
    __shared__ __align__(16) unsigned short sB[D * LDA];    // 34816 B
    __shared__ int   sIdx[2 * TM];                          // 1024 B
    __shared__ float sBias[2 * D];                          // 1024 B

    const int tid  = threadIdx.x;
    const int lane = tid & 63;
    const int wave = tid >> 6;
    const int e0   = blockIdx.x * TM;
    const int seg  = tid & 15;        // 16B segment within a 128-elem row
    const int rb   = tid >> 4;        // base row (0..15)

    // stage indices + biases
    if (tid < TM) sIdx[tid] = sidx[e0 + tid];
    else          sIdx[tid] = ridx[e0 + tid - TM];
    sBias[tid] = (tid < D) ? b1[tid] : b2[tid - D];

    const int l16  = lane & 15;
    const int quad = lane >> 4;

    f32x4 acc[2][8];
#pragma unroll
    for (int i = 0; i < 2; ++i)
#pragma unroll
        for (int j = 0; j < 8; ++j)
            acc[i][j] = (f32x4){0.f, 0.f, 0.f, 0.f};

    // ---------------- GEMM1: 3 K-chunks of 128 ----------------
    for (int c = 0; c < 3; ++c) {
        __syncthreads();   // prev chunk fully consumed (also covers sIdx/sBias on c==0)

        // stage A chunk (128 rows x 128 bf16)
        if (c < 2) {
#pragma unroll
            for (int it = 0; it < 8; ++it) {
                int row = rb + it * 16;
                int node = sIdx[c * TM + row];
                if (CELL_BF16) {
                    uint4 v = *(const uint4*)(cellb + node * D + seg * 8);
                    *(uint4*)(&sA[row * LDA + seg * 8]) = v;
                } else {
                    const float* src = cell_f32 + (size_t)node * D + seg * 8;
                    float4 f0 = *(const float4*)(src);
                    float4 f1 = *(const float4*)(src + 4);
                    uint4 v;
                    v.x = bf16_rne(f0.x) | (bf16_rne(f0.y) << 16);
                    v.y = bf16_rne(f0.z) | (bf16_rne(f0.w) << 16);
                    v.z = bf16_rne(f1.x) | (bf16_rne(f1.y) << 16);
                    v.w = bf16_rne(f1.z) | (bf16_rne(f1.w) << 16);
                    *(uint4*)(&sA[row * LDA + seg * 8]) = v;
                }
            }
        } else {
#pragma unroll
            for (int it = 0; it < 8; ++it) {
                int row = rb + it * 16;
                const float* src = edge_attr + (size_t)(e0 + row) * D + seg * 8;
                float4 f0 = *(const float4*)(src);
                float4 f1 = *(const float4*)(src + 4);
                uint4 v;
                v.x = bf16_rne(f0.x) | (bf16_rne(f0.y) << 16);
                v.y = bf16_rne(f0.z) | (bf16_rne(f0.w) << 16);
                v.z = bf16_rne(f1.x) | (bf16_rne(f1.y) << 16);
                v.w = bf16_rne(f1.z) | (bf16_rne(f1.w) << 16);
                *(uint4*)(&sA[row * LDA + seg * 8]) = v;
            }
        }
        // stage B chunk: sB[n][k] = W1T[n][c*128 + k]
#pragma unroll
        for (int it = 0; it < 8; ++it) {
            int row = rb + it * 16;
            uint4 v = *(const uint4*)(W1T + row * K1 + c * D + seg * 8);
            *(uint4*)(&sB[row * LDA + seg * 8]) = v;
        }
        __syncthreads();

        // compute: wave owns M rows [wave*32, wave*32+32)
#pragma unroll
        for (int kk = 0; kk < 4; ++kk) {
            const int ko = kk * 32 + quad * 8;
            short8 a0 = *(const short8*)(&sA[(wave * 32 + l16) * LDA + ko]);
            short8 a1 = *(const short8*)(&sA[(wave * 32 + 16 + l16) * LDA + ko]);
#pragma unroll
            for (int nt = 0; nt < 8; ++nt) {
                short8 b = *(const short8*)(&sB[(nt * 16 + l16) * LDA + ko]);
                acc[0][nt] = __builtin_amdgcn_mfma_f32_16x16x32_bf16(a0, b, acc[0][nt], 0, 0, 0);
                acc[1][nt] = __builtin_amdgcn_mfma_f32_16x16x32_bf16(a1, b, acc[1][nt], 0, 0, 0);
            }
        }
    }

    // ---------------- relu + b1, h -> LDS (A layout, bf16) ----------------
    // C/D layout: row = quad*4 + r (within 16-tile), col = l16
#pragma unroll
    for (int mt = 0; mt < 2; ++mt) {
        const int mbase = wave * 32 + mt * 16 + quad * 4;
#pragma unroll
        for (int nt = 0; nt < 8; ++nt) {
            const int n = nt * 16 + l16;
            const float bias = sBias[n];
#pragma unroll
            for (int r = 0; r < 4; ++r) {
                float v = acc[mt][nt][r] + bias;
                v = v > 0.f ? v : 0.f;
                sA[(mbase + r) * LDA + n] = (unsigned short)bf16_rne(v);
            }
        }
    }
    __syncthreads();   // h visible; everyone done reading sB

    // stage W2T into sB
#pragma unroll
    for (int it = 0; it < 8; ++it) {
        int row = rb + it * 16;
        uint4 v = *(const uint4*)(W2T + row * D + seg * 8);
        *(uint4*)(&sB[row * LDA + seg * 8]) = v;
    }
    __syncthreads();

    // ---------------- GEMM2: out = h @ W2 + b2 ----------------
    f32x4 acc2[2][8];
#pragma unroll
    for (int i = 0; i < 2; ++i)
#pragma unroll
        for (int j = 0; j < 8; ++j)
            acc2[i][j] = (f32x4){0.f, 0.f, 0.f, 0.f};

#pragma unroll
    for (int kk = 0; kk < 4; ++kk) {
        const int ko = kk * 32 + quad * 8;
        short8 a0 = *(const short8*)(&sA[(wave * 32 + l16) * LDA + ko]);
        short8 a1 = *(const short8*)(&sA[(wave * 32 + 16 + l16) * LDA + ko]);
#pragma unroll
        for (int nt = 0; nt < 8; ++nt) {
            short8 b = *(const short8*)(&sB[(nt * 16 + l16) * LDA + ko]);
            acc2[0][nt] = __builtin_amdgcn_mfma_f32_16x16x32_bf16(a0, b, acc2[0][nt], 0, 0, 0);
            acc2[1][nt] = __builtin_amdgcn_mfma_f32_16x16x32_bf16(a1, b, acc2[1][nt], 0, 0, 0);
        }
    }

    // epilogue: + b2, fp32 stores
#pragma unroll
    for (int mt = 0; mt < 2; ++mt) {
        const int mbase = wave * 32 + mt * 16 + quad * 4;
#pragma unroll
        for (int nt = 0; nt < 8; ++nt) {
            const int n = nt * 16 + l16;
            const float bias = sBias[D + n];
#pragma unroll
            for (int r = 0; r < 4; ++r) {
                out[(size_t)(e0 + mbase + r) * D + n] = acc2[mt][nt][r] + bias;
            }
        }
    }
}

extern "C" void kernel_launch(void* const* d_in, const int* in_sizes, int n_in,
                              void* d_out, int out_size, void* d_ws, size_t ws_size,
                              hipStream_t stream) {
    const float* cell = (const float*)d_in[0];
    const float* edge = (const float*)d_in[1];
    const float* W1   = (const float*)d_in[2];
    const float* b1   = (const float*)d_in[3];
    const float* W2   = (const float*)d_in[4];
    const float* b2   = (const float*)d_in[5];
    const int*   eidx = (const int*)d_in[6];

    const size_t cell_bytes = (size_t)N_NODES * D * 2;      // 12.8 MB
    const size_t w1t_bytes  = (size_t)K1 * D * 2;           // 98304
    const size_t w2t_bytes  = (size_t)D * D * 2;            // 32768

    bool cell_in_ws = ws_size >= cell_bytes + w1t_bytes + w2t_bytes;
    unsigned short* cellb;
    unsigned short* W1T;
    if (cell_in_ws) {
        cellb = (unsigned short*)d_ws;
        W1T   = (unsigned short*)((char*)d_ws + cell_bytes);
    } else {
        cellb = nullptr;
        W1T   = (unsigned short*)d_ws;
    }
    unsigned short* W2T = W1T + K1 * D;

    if (cell_in_ws) {
        int n4 = N_NODES * D / 4;   // 1.6M float4s
        prep_cell<<<(n4 + 255) / 256, 256, 0, stream>>>(cell, cellb, n4);
    }
    prep_w<<<(K1 * D + D * D) / 256, 256, 0, stream>>>(W1, W2, W1T, W2T);

    const int* sidx = eidx;
    const int* ridx = eidx + N_EDGES;
    if (cell_in_ws) {
        edge_mlp<true><<<N_EDGES / TM, 256, 0, stream>>>(
            cell, cellb, edge, W1T, b1, W2T, b2, sidx, ridx, (float*)d_out);
    } else {
        edge_mlp<false><<<N_EDGES / TM, 256, 0, stream>>>(
            cell, cellb, edge, W1T, b1, W2T, b2, sidx, ridx, (float*)d_out);
    }
}